// Round 1
// baseline (1383.939 us; speedup 1.0000x reference)
//
#include <hip/hip_runtime.h>
#include <hip/hip_bf16.h>
#include <math.h>

#define BB 32
#define SS 128
#define DIN 17
#define DPT 64
#define DPA 128
#define DOU 64
#define NP 8256               // SS*(SS+1)/2
#define NROWS (BB * NP)       // 264192
#define NBLK 2048
#define CHUNK 16
#define EPSF 1e-5f

typedef __hip_bfloat16 bf16;

__device__ __forceinline__ float gelu_exact(float x) {
    return 0.5f * x * (1.0f + erff(x * 0.7071067811865476f));
}

// ---------------- K0: pair index table (i<<8 | j), tril order ----------------
__global__ void k_pairs(int* __restrict__ pairIJ) {
    int p = blockIdx.x * blockDim.x + threadIdx.x;
    if (p >= NP) return;
    int i = (int)((sqrtf(8.0f * (float)p + 1.0f) - 1.0f) * 0.5f);
    while ((i * (i + 1)) / 2 > p) --i;
    while (((i + 1) * (i + 2)) / 2 <= p) ++i;
    int j = p - (i * (i + 1)) / 2;
    pairIJ[p] = (i << 8) | j;
}

// ---------------- K1: h = gelu(gelu(x@w1+b1)@w2+b2), 4096 rows ---------------
__global__ void k_h(const float* __restrict__ x, const float* __restrict__ w1,
                    const float* __restrict__ b1, const float* __restrict__ w2,
                    const float* __restrict__ b2, float* __restrict__ h) {
    __shared__ float h1[4][DPT];
    int t = threadIdx.x;
    int rs = t >> 6;                 // row slot 0..3
    int c = t & 63;
    int r = blockIdx.x * 4 + rs;     // global row 0..4095
    const float* xr = x + (size_t)r * DIN;
    float acc = b1[c];
#pragma unroll
    for (int k = 0; k < DIN; ++k) acc += xr[k] * w1[k * DPT + c];
    h1[rs][c] = gelu_exact(acc);
    __syncthreads();
    float acc2 = b2[c];
#pragma unroll
    for (int k = 0; k < DPT; ++k) acc2 += h1[rs][k] * w2[k * DPT + c];
    h[(size_t)r * DPT + c] = gelu_exact(acc2);
}

// -------- K2: e0 = gelu(gelu(xij@wp1+bp1)@wp2+bp2); partial stats ------------
__global__ __launch_bounds__(256, 1) void k_e0(
    const float* __restrict__ h, const int* __restrict__ pairIJ,
    const float* __restrict__ wp1, const float* __restrict__ bp1,
    const float* __restrict__ wp2, const float* __restrict__ bp2,
    bf16* __restrict__ e0, float* __restrict__ part) {
    __shared__ float w1s[DPA][DPA];   // 64 KB
    __shared__ float w2s[DPA][DPA];   // 64 KB
    __shared__ float xs[CHUNK][DPA];  // 8 KB
    int t = threadIdx.x;
    for (int idx = t; idx < DPA * DPA; idx += 256) {
        w1s[idx >> 7][idx & 127] = wp1[idx];
        w2s[idx >> 7][idx & 127] = wp2[idx];
    }
    int r = t >> 4;   // row slot 0..15
    int m = t & 15;   // channel lane 0..15; channels m+16*cc
    float sum[8], sq[8];
#pragma unroll
    for (int cc = 0; cc < 8; ++cc) { sum[cc] = 0.f; sq[cc] = 0.f; }
    const int nChunks = NROWS / CHUNK;  // 16512
    __syncthreads();
    for (int ch = blockIdx.x; ch < nChunks; ch += gridDim.x) {
        int row0 = ch * CHUNK;
        // gather xij: [0:64]=h[b][j], [64:128]=h[b][i]
        for (int idx = t; idx < CHUNK * DPA; idx += 256) {
            int rr = idx >> 7, c = idx & 127;
            int n = row0 + rr;
            int b = n / NP, p = n - b * NP;
            int ij = pairIJ[p];
            int ii = ij >> 8, jj = ij & 255;
            int src = (c < 64) ? jj : ii;
            xs[rr][c] = h[(size_t)(b * SS + src) * DPT + (c & 63)];
        }
        __syncthreads();
        float acc[8];
#pragma unroll
        for (int cc = 0; cc < 8; ++cc) acc[cc] = bp1[m + 16 * cc];
        for (int k = 0; k < DPA; ++k) {
            float xv = xs[r][k];
#pragma unroll
            for (int cc = 0; cc < 8; ++cc) acc[cc] += xv * w1s[k][m + 16 * cc];
        }
        __syncthreads();
#pragma unroll
        for (int cc = 0; cc < 8; ++cc) xs[r][m + 16 * cc] = gelu_exact(acc[cc]);
        __syncthreads();
#pragma unroll
        for (int cc = 0; cc < 8; ++cc) acc[cc] = bp2[m + 16 * cc];
        for (int k = 0; k < DPA; ++k) {
            float xv = xs[r][k];
#pragma unroll
            for (int cc = 0; cc < 8; ++cc) acc[cc] += xv * w2s[k][m + 16 * cc];
        }
        __syncthreads();
#pragma unroll
        for (int cc = 0; cc < 8; ++cc) {
            float v = gelu_exact(acc[cc]);
            xs[r][m + 16 * cc] = v;
            sum[cc] += v;
            sq[cc] += v * v;
        }
        __syncthreads();
        for (int idx = t; idx < CHUNK * DPA; idx += 256) {
            int rr = idx >> 7, c = idx & 127;
            e0[(size_t)(row0 + rr) * DPA + c] = __float2bfloat16(xs[rr][c]);
        }
        __syncthreads();
    }
    // deterministic block reduce: 256 floats [sum(128) | sq(128)]
    float* red = &xs[0][0];
    red[t] = 0.f;
    __syncthreads();
    for (int step = 0; step < 16; ++step) {
        if (r == step) {
#pragma unroll
            for (int cc = 0; cc < 8; ++cc) {
                red[m + 16 * cc] += sum[cc];
                red[128 + m + 16 * cc] += sq[cc];
            }
        }
        __syncthreads();
    }
    part[(size_t)blockIdx.x * 256 + t] = red[t];
}

// -------- stats finalize: a = g*rstd, d = be - mean*a (block per channel) ----
__global__ void k_stats(const float* __restrict__ part, int nch,
                        float* __restrict__ a, float* __restrict__ d,
                        const float* __restrict__ g, const float* __restrict__ be) {
    int c = blockIdx.x;
    __shared__ float ssum[256], ssq[256];
    float s = 0.f, q = 0.f;
    for (int bidx = threadIdx.x; bidx < NBLK; bidx += 256) {
        s += part[(size_t)bidx * (2 * nch) + c];
        q += part[(size_t)bidx * (2 * nch) + nch + c];
    }
    ssum[threadIdx.x] = s;
    ssq[threadIdx.x] = q;
    __syncthreads();
    for (int w = 128; w > 0; w >>= 1) {
        if ((int)threadIdx.x < w) {
            ssum[threadIdx.x] += ssum[threadIdx.x + w];
            ssq[threadIdx.x] += ssq[threadIdx.x + w];
        }
        __syncthreads();
    }
    if (threadIdx.x == 0) {
        float mean = ssum[0] / (float)NROWS;
        float var = ssq[0] / (float)NROWS - mean * mean;
        float rstd = rsqrtf(var + EPSF);
        float aa = g[c] * rstd;
        a[c] = aa;
        d[c] = be[c] - mean * aa;
    }
}

// -------- K4: e1 = bn0(e0)@wc1 + bc1; partial stats --------------------------
__global__ __launch_bounds__(256, 2) void k_e1(
    const bf16* __restrict__ e0, const float* __restrict__ a0,
    const float* __restrict__ d0, const float* __restrict__ wc1,
    const float* __restrict__ bc1, bf16* __restrict__ e1,
    float* __restrict__ part) {
    __shared__ float wsh[DPA][DOU];   // 32 KB
    __shared__ float xs[CHUNK][DPA];  // 8 KB
    int t = threadIdx.x;
    for (int idx = t; idx < DPA * DOU; idx += 256) wsh[idx >> 6][idx & 63] = wc1[idx];
    int r = t >> 4, m = t & 15;
    float sum[4], sq[4];
#pragma unroll
    for (int cc = 0; cc < 4; ++cc) { sum[cc] = 0.f; sq[cc] = 0.f; }
    const int nChunks = NROWS / CHUNK;
    __syncthreads();
    for (int ch = blockIdx.x; ch < nChunks; ch += gridDim.x) {
        size_t row0 = (size_t)ch * CHUNK;
        for (int idx = t; idx < CHUNK * DPA; idx += 256) {
            int rr = idx >> 7, c = idx & 127;
            float v = __bfloat162float(e0[(row0 + rr) * DPA + c]);
            xs[rr][c] = a0[c] * v + d0[c];
        }
        __syncthreads();
        float acc[4];
#pragma unroll
        for (int cc = 0; cc < 4; ++cc) acc[cc] = bc1[m + 16 * cc];
        for (int k = 0; k < DPA; ++k) {
            float xv = xs[r][k];
#pragma unroll
            for (int cc = 0; cc < 4; ++cc) acc[cc] += xv * wsh[k][m + 16 * cc];
        }
#pragma unroll
        for (int cc = 0; cc < 4; ++cc) { sum[cc] += acc[cc]; sq[cc] += acc[cc] * acc[cc]; }
        __syncthreads();
#pragma unroll
        for (int cc = 0; cc < 4; ++cc) xs[r][m + 16 * cc] = acc[cc];
        __syncthreads();
        for (int idx = t; idx < CHUNK * DOU; idx += 256) {
            int rr = idx >> 6, c = idx & 63;
            e1[(row0 + rr) * DOU + c] = __float2bfloat16(xs[rr][c]);
        }
        __syncthreads();
    }
    float* red = &xs[0][0];  // 128 floats [sum(64) | sq(64)]
    if (t < 128) red[t] = 0.f;
    __syncthreads();
    for (int step = 0; step < 16; ++step) {
        if (r == step) {
#pragma unroll
            for (int cc = 0; cc < 4; ++cc) {
                red[m + 16 * cc] += sum[cc];
                red[64 + m + 16 * cc] += sq[cc];
            }
        }
        __syncthreads();
    }
    if (t < 128) part[(size_t)blockIdx.x * 128 + t] = red[t];
}

// -------- K6: e2 = gelu(bn1(e1))@wc2 + bc2; partial stats --------------------
__global__ __launch_bounds__(256, 2) void k_e2k(
    const bf16* __restrict__ e1, const float* __restrict__ a1,
    const float* __restrict__ d1, const float* __restrict__ wc2,
    const float* __restrict__ bc2, bf16* __restrict__ e2,
    float* __restrict__ part) {
    __shared__ float wsh[DOU][DOU];   // 16 KB
    __shared__ float xs[CHUNK][DOU];  // 4 KB
    int t = threadIdx.x;
    for (int idx = t; idx < DOU * DOU; idx += 256) wsh[idx >> 6][idx & 63] = wc2[idx];
    int r = t >> 4, m = t & 15;
    float sum[4], sq[4];
#pragma unroll
    for (int cc = 0; cc < 4; ++cc) { sum[cc] = 0.f; sq[cc] = 0.f; }
    const int nChunks = NROWS / CHUNK;
    __syncthreads();
    for (int ch = blockIdx.x; ch < nChunks; ch += gridDim.x) {
        size_t row0 = (size_t)ch * CHUNK;
        for (int idx = t; idx < CHUNK * DOU; idx += 256) {
            int rr = idx >> 6, c = idx & 63;
            float v = __bfloat162float(e1[(row0 + rr) * DOU + c]);
            xs[rr][c] = gelu_exact(a1[c] * v + d1[c]);
        }
        __syncthreads();
        float acc[4];
#pragma unroll
        for (int cc = 0; cc < 4; ++cc) acc[cc] = bc2[m + 16 * cc];
        for (int k = 0; k < DOU; ++k) {
            float xv = xs[r][k];
#pragma unroll
            for (int cc = 0; cc < 4; ++cc) acc[cc] += xv * wsh[k][m + 16 * cc];
        }
#pragma unroll
        for (int cc = 0; cc < 4; ++cc) { sum[cc] += acc[cc]; sq[cc] += acc[cc] * acc[cc]; }
        __syncthreads();
#pragma unroll
        for (int cc = 0; cc < 4; ++cc) xs[r][m + 16 * cc] = acc[cc];
        __syncthreads();
        for (int idx = t; idx < CHUNK * DOU; idx += 256) {
            int rr = idx >> 6, c = idx & 63;
            e2[(row0 + rr) * DOU + c] = __float2bfloat16(xs[rr][c]);
        }
        __syncthreads();
    }
    float* red = &xs[0][0];
    if (t < 128) red[t] = 0.f;
    __syncthreads();
    for (int step = 0; step < 16; ++step) {
        if (r == step) {
#pragma unroll
            for (int cc = 0; cc < 4; ++cc) {
                red[m + 16 * cc] += sum[cc];
                red[64 + m + 16 * cc] += sq[cc];
            }
        }
        __syncthreads();
    }
    if (t < 128) part[(size_t)blockIdx.x * 128 + t] = red[t];
}

// -------- K8: y[b,i,j,:] = y[b,j,i,:] = bn2(e2) ------------------------------
__global__ void k_out(const bf16* __restrict__ e2, const int* __restrict__ pairIJ,
                      const float* __restrict__ a2, const float* __restrict__ d2,
                      float* __restrict__ y) {
    int t = threadIdx.x;
    int n = blockIdx.x * 4 + (t >> 6);  // pair row
    int c = t & 63;
    int b = n / NP, p = n - b * NP;
    int ij = pairIJ[p];
    int ii = ij >> 8, jj = ij & 255;
    float v = a2[c] * __bfloat162float(e2[(size_t)n * DOU + c]) + d2[c];
    y[((size_t)(b * SS + ii) * SS + jj) * DOU + c] = v;
    y[((size_t)(b * SS + jj) * SS + ii) * DOU + c] = v;
}

extern "C" void kernel_launch(void* const* d_in, const int* in_sizes, int n_in,
                              void* d_out, int out_size, void* d_ws, size_t ws_size,
                              hipStream_t stream) {
    const float* x   = (const float*)d_in[0];
    const float* w1  = (const float*)d_in[1];
    const float* b1  = (const float*)d_in[2];
    const float* w2  = (const float*)d_in[3];
    const float* b2  = (const float*)d_in[4];
    const float* wp1 = (const float*)d_in[5];
    const float* bp1 = (const float*)d_in[6];
    const float* wp2 = (const float*)d_in[7];
    const float* bp2 = (const float*)d_in[8];
    const float* g0  = (const float*)d_in[9];
    const float* be0 = (const float*)d_in[10];
    const float* wc1 = (const float*)d_in[11];
    const float* bc1 = (const float*)d_in[12];
    const float* g1  = (const float*)d_in[13];
    const float* be1 = (const float*)d_in[14];
    const float* wc2 = (const float*)d_in[15];
    const float* bc2 = (const float*)d_in[16];
    const float* g2  = (const float*)d_in[17];
    const float* be2 = (const float*)d_in[18];

    char* ws = (char*)d_ws;
    // ws layout (bytes)
    const size_t OFF_PAIR = 0;                       // 33024 B
    const size_t OFF_H    = 33280;                   // 1 MB
    const size_t OFF_PART = OFF_H + 1048576;         // 2 MB (shared by all 3 passes)
    const size_t OFF_A0   = OFF_PART + 2097152;
    const size_t OFF_D0   = OFF_A0 + 512;
    const size_t OFF_A1   = OFF_D0 + 512;
    const size_t OFF_D1   = OFF_A1 + 256;
    const size_t OFF_A2   = OFF_D1 + 256;
    const size_t OFF_D2   = OFF_A2 + 256;
    const size_t OFF_E2   = (OFF_D2 + 256 + 255) & ~(size_t)255;  // 33.8 MB

    int*   pairIJ = (int*)(ws + OFF_PAIR);
    float* h      = (float*)(ws + OFF_H);
    float* part   = (float*)(ws + OFF_PART);
    float* a0 = (float*)(ws + OFF_A0);
    float* d0 = (float*)(ws + OFF_D0);
    float* a1 = (float*)(ws + OFF_A1);
    float* d1 = (float*)(ws + OFF_D1);
    float* a2 = (float*)(ws + OFF_A2);
    float* d2 = (float*)(ws + OFF_D2);
    bf16*  e2 = (bf16*)(ws + OFF_E2);

    // e0/e1 live inside d_out (dead before final scatter overwrites)
    bf16* e0 = (bf16*)d_out;
    bf16* e1 = (bf16*)((char*)d_out + (size_t)NROWS * DPA * sizeof(bf16));
    float* y = (float*)d_out;

    k_pairs<<<(NP + 255) / 256, 256, 0, stream>>>(pairIJ);
    k_h<<<(BB * SS) / 4, 256, 0, stream>>>(x, w1, b1, w2, b2, h);
    k_e0<<<NBLK, 256, 0, stream>>>(h, pairIJ, wp1, bp1, wp2, bp2, e0, part);
    k_stats<<<DPA, 256, 0, stream>>>(part, DPA, a0, d0, g0, be0);
    k_e1<<<NBLK, 256, 0, stream>>>(e0, a0, d0, wc1, bc1, e1, part);
    k_stats<<<DOU, 256, 0, stream>>>(part, DOU, a1, d1, g1, be1);
    k_e2k<<<NBLK, 256, 0, stream>>>(e1, a1, d1, wc2, bc2, e2, part);
    k_stats<<<DOU, 256, 0, stream>>>(part, DOU, a2, d2, g2, be2);
    k_out<<<NROWS / 4, 256, 0, stream>>>(e2, pairIJ, a2, d2, y);
}

// Round 2
// 476.343 us; speedup vs baseline: 2.9053x; 2.9053x over previous
//
#include <hip/hip_runtime.h>
#include <hip/hip_bf16.h>
#include <math.h>

#define BB 32
#define SS 128
#define DIN 17
#define DPT 64
#define DPA 128
#define DOU 64
#define NP 8256               // SS*(SS+1)/2
#define NROWS (BB * NP)       // 264192
#define NBLK 2048
#define GRID0 512
#define CHUNK 16
#define EPSF 1e-5f

typedef __hip_bfloat16 bf16;
typedef __attribute__((ext_vector_type(8))) short short8;
typedef __attribute__((ext_vector_type(16))) float f32x16;
typedef __attribute__((ext_vector_type(4))) int int4v;

#define MFMA32(a, b, c) __builtin_amdgcn_mfma_f32_32x32x16_bf16(a, b, c, 0, 0, 0)

__device__ __forceinline__ unsigned short bfb(float f) {
    return __builtin_bit_cast(unsigned short, __float2bfloat16(f));
}

// exact gelu via A&S 7.1.26 rational poly (|eps| <= 1.5e-7), ~13 VALU ops
__device__ __forceinline__ float gelu_exact(float x) {
    float z = fabsf(x) * 0.7071067811865476f;
    float t = __builtin_amdgcn_rcpf(fmaf(0.3275911f, z, 1.0f));
    float p = fmaf(t, 1.061405429f, -1.453152027f);
    p = fmaf(t, p, 1.421413741f);
    p = fmaf(t, p, -0.284496736f);
    p = fmaf(t, p, 0.254829592f);
    p *= t;
    float e = __expf(-z * z);
    float erfz = 1.0f - p * e;
    float s = copysignf(erfz, x);
    return 0.5f * x * (1.0f + s);
}

// ---------------- K0: pair index table (i<<8 | j), tril order ----------------
__global__ void k_pairs(int* __restrict__ pairIJ) {
    int p = blockIdx.x * blockDim.x + threadIdx.x;
    if (p >= NP) return;
    int i = (int)((sqrtf(8.0f * (float)p + 1.0f) - 1.0f) * 0.5f);
    while ((i * (i + 1)) / 2 > p) --i;
    while (((i + 1) * (i + 2)) / 2 <= p) ++i;
    int j = p - (i * (i + 1)) / 2;
    pairIJ[p] = (i << 8) | j;
}

// ---------------- K1: h = gelu(gelu(x@w1+b1)@w2+b2), bf16 out ----------------
__global__ void k_h(const float* __restrict__ x, const float* __restrict__ w1,
                    const float* __restrict__ b1, const float* __restrict__ w2,
                    const float* __restrict__ b2, bf16* __restrict__ h) {
    __shared__ float h1[4][DPT];
    int t = threadIdx.x;
    int rs = t >> 6;
    int c = t & 63;
    int r = blockIdx.x * 4 + rs;
    const float* xr = x + (size_t)r * DIN;
    float acc = b1[c];
#pragma unroll
    for (int k = 0; k < DIN; ++k) acc += xr[k] * w1[k * DPT + c];
    h1[rs][c] = gelu_exact(acc);
    __syncthreads();
    float acc2 = b2[c];
#pragma unroll
    for (int k = 0; k < DPT; ++k) acc2 += h1[rs][k] * w2[k * DPT + c];
    h[(size_t)r * DPT + c] = __float2bfloat16(gelu_exact(acc2));
}

// -------- K2 (MFMA): e0 = gelu(gelu(xij@wp1+bp1)@wp2+bp2); partial stats -----
// 4 waves in 2x2 grid over a 128x128 chunk; weights hoisted to registers;
// X / mid in XOR-swizzled LDS (byte ^= (row&7)<<4 at 16B granularity).
__global__ __launch_bounds__(256, 2) void k_e0m(
    const bf16* __restrict__ h, const int* __restrict__ pairIJ,
    const float* __restrict__ wp1, const float* __restrict__ bp1,
    const float* __restrict__ wp2, const float* __restrict__ bp2,
    bf16* __restrict__ e0, float* __restrict__ part) {
    __shared__ __align__(16) char lds[69632];  // xs 32K | mid 32K | stats 4K
    const int MID = 32768;
    int t = threadIdx.x;
    int w = t >> 6, l = t & 63;
    int wm = w >> 1, wn = w & 1;
    int l31 = l & 31, lhi = l >> 5;

    // hoist B fragments (both GEMMs) into registers, chunk-invariant
    // B layout: col = lane&31, k = (lane>>5)*8 + i
    short8 b1f[2][8], b2f[2][8];
#pragma unroll
    for (int nt = 0; nt < 2; ++nt) {
        int n = wn * 64 + nt * 32 + l31;
#pragma unroll
        for (int s = 0; s < 8; ++s) {
            int k0 = s * 16 + lhi * 8;
            short8 v1, v2;
#pragma unroll
            for (int i = 0; i < 8; ++i) {
                v1[i] = (short)bfb(wp1[(size_t)(k0 + i) * DPA + n]);
                v2[i] = (short)bfb(wp2[(size_t)(k0 + i) * DPA + n]);
            }
            b1f[nt][s] = v1;
            b2f[nt][s] = v2;
        }
    }
    float bias1[2] = {bp1[wn * 64 + l31], bp1[wn * 64 + 32 + l31]};
    float bias2[2] = {bp2[wn * 64 + l31], bp2[wn * 64 + 32 + l31]};

    float sum[2] = {0.f, 0.f}, sq[2] = {0.f, 0.f};
    const int rA0 = wm * 64 + l31;

    for (int ch = blockIdx.x; ch < NROWS / 128; ch += GRID0) {
        int row0 = ch * 128;
        // gather xij chunk into swizzled LDS (16B tasks)
#pragma unroll
        for (int q = 0; q < 8; ++q) {
            int task = t + 256 * q;       // 0..2047
            int rr = task >> 4, slot = task & 15;
            int n = row0 + rr;
            int b = n / NP, p = n - b * NP;
            int ij = pairIJ[p];
            int src = (slot < 8) ? (ij & 255) : (ij >> 8);
            const bf16* gp = h + (((size_t)(b * SS + src)) << 6) + ((slot & 7) << 3);
            int4v v = *(const int4v*)gp;
            *(int4v*)(lds + rr * 256 + ((slot * 16) ^ ((rr & 7) << 4))) = v;
        }
        __syncthreads();

        // ---- GEMM1: mid = gelu(X @ wp1 + bp1) ----
        f32x16 acc[2][2];
#pragma unroll
        for (int mt = 0; mt < 2; ++mt)
#pragma unroll
            for (int nt = 0; nt < 2; ++nt)
#pragma unroll
                for (int r = 0; r < 16; ++r) acc[mt][nt][r] = bias1[nt];
#pragma unroll
        for (int s = 0; s < 8; ++s) {
            int kb = s * 32 + lhi * 16;
            int r1 = rA0 + 32;
            short8 a0 = *(const short8*)(lds + rA0 * 256 + (kb ^ ((rA0 & 7) << 4)));
            short8 a1 = *(const short8*)(lds + r1 * 256 + (kb ^ ((r1 & 7) << 4)));
            acc[0][0] = MFMA32(a0, b1f[0][s], acc[0][0]);
            acc[0][1] = MFMA32(a0, b1f[1][s], acc[0][1]);
            acc[1][0] = MFMA32(a1, b1f[0][s], acc[1][0]);
            acc[1][1] = MFMA32(a1, b1f[1][s], acc[1][1]);
        }
#pragma unroll
        for (int mt = 0; mt < 2; ++mt)
#pragma unroll
            for (int nt = 0; nt < 2; ++nt)
#pragma unroll
                for (int r = 0; r < 16; ++r) {
                    float v = gelu_exact(acc[mt][nt][r]);
                    int row = wm * 64 + mt * 32 + (r & 3) + 8 * (r >> 2) + 4 * lhi;
                    int col = wn * 64 + nt * 32 + l31;
                    *(bf16*)(lds + MID + row * 256 + ((col * 2) ^ ((row & 7) << 4))) =
                        __float2bfloat16(v);
                }
        __syncthreads();

        // ---- GEMM2: e0 = gelu(mid @ wp2 + bp2) ----
        f32x16 acc2[2][2];
#pragma unroll
        for (int mt = 0; mt < 2; ++mt)
#pragma unroll
            for (int nt = 0; nt < 2; ++nt)
#pragma unroll
                for (int r = 0; r < 16; ++r) acc2[mt][nt][r] = bias2[nt];
#pragma unroll
        for (int s = 0; s < 8; ++s) {
            int kb = s * 32 + lhi * 16;
            int r1 = rA0 + 32;
            short8 a0 = *(const short8*)(lds + MID + rA0 * 256 + (kb ^ ((rA0 & 7) << 4)));
            short8 a1 = *(const short8*)(lds + MID + r1 * 256 + (kb ^ ((r1 & 7) << 4)));
            acc2[0][0] = MFMA32(a0, b2f[0][s], acc2[0][0]);
            acc2[0][1] = MFMA32(a0, b2f[1][s], acc2[0][1]);
            acc2[1][0] = MFMA32(a1, b2f[0][s], acc2[1][0]);
            acc2[1][1] = MFMA32(a1, b2f[1][s], acc2[1][1]);
        }
#pragma unroll
        for (int mt = 0; mt < 2; ++mt)
#pragma unroll
            for (int nt = 0; nt < 2; ++nt)
#pragma unroll
                for (int r = 0; r < 16; ++r) {
                    float v = gelu_exact(acc2[mt][nt][r]);
                    sum[nt] += v;
                    sq[nt] += v * v;
                    int row = row0 + wm * 64 + mt * 32 + (r & 3) + 8 * (r >> 2) + 4 * lhi;
                    int col = wn * 64 + nt * 32 + l31;
                    e0[(size_t)row * DPA + col] = __float2bfloat16(v);
                }
    }

    // ---- stats: lane-pair reduce, then cross-wave via LDS ----
#pragma unroll
    for (int nt = 0; nt < 2; ++nt) {
        sum[nt] += __shfl_xor(sum[nt], 32);
        sq[nt] += __shfl_xor(sq[nt], 32);
    }
    float* st = (float*)lds;  // 1024 floats, reuse xs region
    __syncthreads();
    for (int i = t; i < 1024; i += 256) st[i] = 0.f;
    __syncthreads();
    if (l < 32) {
#pragma unroll
        for (int nt = 0; nt < 2; ++nt) {
            st[w * 256 + wn * 64 + nt * 32 + l31] = sum[nt];
            st[w * 256 + 128 + wn * 64 + nt * 32 + l31] = sq[nt];
        }
    }
    __syncthreads();
    if (t < 256)
        part[(size_t)blockIdx.x * 256 + t] = st[t] + st[256 + t] + st[512 + t] + st[768 + t];
}

// -------- stats finalize: a = g*rstd, d = be - mean*a (block per channel) ----
__global__ void k_stats(const float* __restrict__ part, int nch, int nblk,
                        float* __restrict__ a, float* __restrict__ d,
                        const float* __restrict__ g, const float* __restrict__ be) {
    int c = blockIdx.x;
    __shared__ float ssum[256], ssq[256];
    float s = 0.f, q = 0.f;
    for (int bidx = threadIdx.x; bidx < nblk; bidx += 256) {
        s += part[(size_t)bidx * (2 * nch) + c];
        q += part[(size_t)bidx * (2 * nch) + nch + c];
    }
    ssum[threadIdx.x] = s;
    ssq[threadIdx.x] = q;
    __syncthreads();
    for (int w = 128; w > 0; w >>= 1) {
        if ((int)threadIdx.x < w) {
            ssum[threadIdx.x] += ssum[threadIdx.x + w];
            ssq[threadIdx.x] += ssq[threadIdx.x + w];
        }
        __syncthreads();
    }
    if (threadIdx.x == 0) {
        float mean = ssum[0] / (float)NROWS;
        float var = ssq[0] / (float)NROWS - mean * mean;
        float rstd = rsqrtf(var + EPSF);
        float aa = g[c] * rstd;
        a[c] = aa;
        d[c] = be[c] - mean * aa;
    }
}

// -------- K4: e1 = bn0(e0)@wc1 + bc1; partial stats --------------------------
__global__ __launch_bounds__(256, 2) void k_e1(
    const bf16* __restrict__ e0, const float* __restrict__ a0,
    const float* __restrict__ d0, const float* __restrict__ wc1,
    const float* __restrict__ bc1, bf16* __restrict__ e1,
    float* __restrict__ part) {
    __shared__ float wsh[DPA][DOU];
    __shared__ float xs[CHUNK][DPA];
    int t = threadIdx.x;
    for (int idx = t; idx < DPA * DOU; idx += 256) wsh[idx >> 6][idx & 63] = wc1[idx];
    int r = t >> 4, m = t & 15;
    float sum[4], sq[4];
#pragma unroll
    for (int cc = 0; cc < 4; ++cc) { sum[cc] = 0.f; sq[cc] = 0.f; }
    const int nChunks = NROWS / CHUNK;
    __syncthreads();
    for (int ch = blockIdx.x; ch < nChunks; ch += gridDim.x) {
        size_t row0 = (size_t)ch * CHUNK;
        for (int idx = t; idx < CHUNK * DPA; idx += 256) {
            int rr = idx >> 7, c = idx & 127;
            float v = __bfloat162float(e0[(row0 + rr) * DPA + c]);
            xs[rr][c] = a0[c] * v + d0[c];
        }
        __syncthreads();
        float acc[4];
#pragma unroll
        for (int cc = 0; cc < 4; ++cc) acc[cc] = bc1[m + 16 * cc];
        for (int k = 0; k < DPA; ++k) {
            float xv = xs[r][k];
#pragma unroll
            for (int cc = 0; cc < 4; ++cc) acc[cc] += xv * wsh[k][m + 16 * cc];
        }
#pragma unroll
        for (int cc = 0; cc < 4; ++cc) { sum[cc] += acc[cc]; sq[cc] += acc[cc] * acc[cc]; }
        __syncthreads();
#pragma unroll
        for (int cc = 0; cc < 4; ++cc) xs[r][m + 16 * cc] = acc[cc];
        __syncthreads();
        for (int idx = t; idx < CHUNK * DOU; idx += 256) {
            int rr = idx >> 6, c = idx & 63;
            e1[(row0 + rr) * DOU + c] = __float2bfloat16(xs[rr][c]);
        }
        __syncthreads();
    }
    float* red = &xs[0][0];
    if (t < 128) red[t] = 0.f;
    __syncthreads();
    for (int step = 0; step < 16; ++step) {
        if (r == step) {
#pragma unroll
            for (int cc = 0; cc < 4; ++cc) {
                red[m + 16 * cc] += sum[cc];
                red[64 + m + 16 * cc] += sq[cc];
            }
        }
        __syncthreads();
    }
    if (t < 128) part[(size_t)blockIdx.x * 128 + t] = red[t];
}

// -------- K6: e2 = gelu(bn1(e1))@wc2 + bc2; partial stats --------------------
__global__ __launch_bounds__(256, 2) void k_e2k(
    const bf16* __restrict__ e1, const float* __restrict__ a1,
    const float* __restrict__ d1, const float* __restrict__ wc2,
    const float* __restrict__ bc2, bf16* __restrict__ e2,
    float* __restrict__ part) {
    __shared__ float wsh[DOU][DOU];
    __shared__ float xs[CHUNK][DOU];
    int t = threadIdx.x;
    for (int idx = t; idx < DOU * DOU; idx += 256) wsh[idx >> 6][idx & 63] = wc2[idx];
    int r = t >> 4, m = t & 15;
    float sum[4], sq[4];
#pragma unroll
    for (int cc = 0; cc < 4; ++cc) { sum[cc] = 0.f; sq[cc] = 0.f; }
    const int nChunks = NROWS / CHUNK;
    __syncthreads();
    for (int ch = blockIdx.x; ch < nChunks; ch += gridDim.x) {
        size_t row0 = (size_t)ch * CHUNK;
        for (int idx = t; idx < CHUNK * DOU; idx += 256) {
            int rr = idx >> 6, c = idx & 63;
            float v = __bfloat162float(e1[(row0 + rr) * DOU + c]);
            xs[rr][c] = gelu_exact(a1[c] * v + d1[c]);
        }
        __syncthreads();
        float acc[4];
#pragma unroll
        for (int cc = 0; cc < 4; ++cc) acc[cc] = bc2[m + 16 * cc];
        for (int k = 0; k < DOU; ++k) {
            float xv = xs[r][k];
#pragma unroll
            for (int cc = 0; cc < 4; ++cc) acc[cc] += xv * wsh[k][m + 16 * cc];
        }
#pragma unroll
        for (int cc = 0; cc < 4; ++cc) { sum[cc] += acc[cc]; sq[cc] += acc[cc] * acc[cc]; }
        __syncthreads();
#pragma unroll
        for (int cc = 0; cc < 4; ++cc) xs[r][m + 16 * cc] = acc[cc];
        __syncthreads();
        for (int idx = t; idx < CHUNK * DOU; idx += 256) {
            int rr = idx >> 6, c = idx & 63;
            e2[(row0 + rr) * DOU + c] = __float2bfloat16(xs[rr][c]);
        }
        __syncthreads();
    }
    float* red = &xs[0][0];
    if (t < 128) red[t] = 0.f;
    __syncthreads();
    for (int step = 0; step < 16; ++step) {
        if (r == step) {
#pragma unroll
            for (int cc = 0; cc < 4; ++cc) {
                red[m + 16 * cc] += sum[cc];
                red[64 + m + 16 * cc] += sq[cc];
            }
        }
        __syncthreads();
    }
    if (t < 128) part[(size_t)blockIdx.x * 128 + t] = red[t];
}

// -------- K8: y[b,i,j,:] = y[b,j,i,:] = bn2(e2) ------------------------------
__global__ void k_out(const bf16* __restrict__ e2, const int* __restrict__ pairIJ,
                      const float* __restrict__ a2, const float* __restrict__ d2,
                      float* __restrict__ y) {
    int t = threadIdx.x;
    int n = blockIdx.x * 4 + (t >> 6);
    int c = t & 63;
    int b = n / NP, p = n - b * NP;
    int ij = pairIJ[p];
    int ii = ij >> 8, jj = ij & 255;
    float v = a2[c] * __bfloat162float(e2[(size_t)n * DOU + c]) + d2[c];
    y[((size_t)(b * SS + ii) * SS + jj) * DOU + c] = v;
    y[((size_t)(b * SS + jj) * SS + ii) * DOU + c] = v;
}

extern "C" void kernel_launch(void* const* d_in, const int* in_sizes, int n_in,
                              void* d_out, int out_size, void* d_ws, size_t ws_size,
                              hipStream_t stream) {
    const float* x   = (const float*)d_in[0];
    const float* w1  = (const float*)d_in[1];
    const float* b1  = (const float*)d_in[2];
    const float* w2  = (const float*)d_in[3];
    const float* b2  = (const float*)d_in[4];
    const float* wp1 = (const float*)d_in[5];
    const float* bp1 = (const float*)d_in[6];
    const float* wp2 = (const float*)d_in[7];
    const float* bp2 = (const float*)d_in[8];
    const float* g0  = (const float*)d_in[9];
    const float* be0 = (const float*)d_in[10];
    const float* wc1 = (const float*)d_in[11];
    const float* bc1 = (const float*)d_in[12];
    const float* g1  = (const float*)d_in[13];
    const float* be1 = (const float*)d_in[14];
    const float* wc2 = (const float*)d_in[15];
    const float* bc2 = (const float*)d_in[16];
    const float* g2  = (const float*)d_in[17];
    const float* be2 = (const float*)d_in[18];

    char* ws = (char*)d_ws;
    const size_t OFF_PAIR = 0;
    const size_t OFF_H    = 33280;
    const size_t OFF_PART = OFF_H + 1048576;
    const size_t OFF_A0   = OFF_PART + 2097152;
    const size_t OFF_D0   = OFF_A0 + 512;
    const size_t OFF_A1   = OFF_D0 + 512;
    const size_t OFF_D1   = OFF_A1 + 256;
    const size_t OFF_A2   = OFF_D1 + 256;
    const size_t OFF_D2   = OFF_A2 + 256;
    const size_t OFF_E2   = (OFF_D2 + 256 + 255) & ~(size_t)255;

    int*   pairIJ = (int*)(ws + OFF_PAIR);
    bf16*  h      = (bf16*)(ws + OFF_H);
    float* part   = (float*)(ws + OFF_PART);
    float* a0 = (float*)(ws + OFF_A0);
    float* d0 = (float*)(ws + OFF_D0);
    float* a1 = (float*)(ws + OFF_A1);
    float* d1 = (float*)(ws + OFF_D1);
    float* a2 = (float*)(ws + OFF_A2);
    float* d2 = (float*)(ws + OFF_D2);
    bf16*  e2 = (bf16*)(ws + OFF_E2);

    bf16* e0 = (bf16*)d_out;
    bf16* e1 = (bf16*)((char*)d_out + (size_t)NROWS * DPA * sizeof(bf16));
    float* y = (float*)d_out;

    k_pairs<<<(NP + 255) / 256, 256, 0, stream>>>(pairIJ);
    k_h<<<(BB * SS) / 4, 256, 0, stream>>>(x, w1, b1, w2, b2, h);
    k_e0m<<<GRID0, 256, 0, stream>>>(h, pairIJ, wp1, bp1, wp2, bp2, e0, part);
    k_stats<<<DPA, 256, 0, stream>>>(part, DPA, GRID0, a0, d0, g0, be0);
    k_e1<<<NBLK, 256, 0, stream>>>(e0, a0, d0, wc1, bc1, e1, part);
    k_stats<<<DOU, 256, 0, stream>>>(part, DOU, NBLK, a1, d1, g1, be1);
    k_e2k<<<NBLK, 256, 0, stream>>>(e1, a1, d1, wc2, bc2, e2, part);
    k_stats<<<DOU, 256, 0, stream>>>(part, DOU, NBLK, a2, d2, g2, be2);
    k_out<<<NROWS / 4, 256, 0, stream>>>(e2, pairIJ, a2, d2, y);
}

// Round 3
// 161.197 us; speedup vs baseline: 8.5854x; 2.9550x over previous
//
#include <hip/hip_runtime.h>
#include <hip/hip_bf16.h>
#include <math.h>

#define BB 32
#define SS 128
#define DIN 17
#define DPT 64
#define DPA 128
#define DOU 64
#define NP 8256               // SS*(SS+1)/2
#define NROWS (BB * NP)       // 264192
#define NCHUNK (NROWS / 128)  // 2064
#define EPSF 1e-5f

typedef __hip_bfloat16 bf16;
typedef __attribute__((ext_vector_type(8))) short short8;
typedef __attribute__((ext_vector_type(16))) float f32x16;
typedef __attribute__((ext_vector_type(4))) float f32x4;
typedef __attribute__((ext_vector_type(4))) int int4v;

#define MFMA32(a, b, c) __builtin_amdgcn_mfma_f32_32x32x16_bf16(a, b, c, 0, 0, 0)

__device__ __forceinline__ unsigned short bfb(float f) {
    return __builtin_bit_cast(unsigned short, __float2bfloat16(f));
}
__device__ __forceinline__ float bf2f(short u) {
    return __builtin_bit_cast(float, ((unsigned int)(unsigned short)u) << 16);
}

// exact gelu via A&S 7.1.26 rational poly (|eps| <= 1.5e-7)
__device__ __forceinline__ float gelu_exact(float x) {
    float z = fabsf(x) * 0.7071067811865476f;
    float t = __builtin_amdgcn_rcpf(fmaf(0.3275911f, z, 1.0f));
    float p = fmaf(t, 1.061405429f, -1.453152027f);
    p = fmaf(t, p, 1.421413741f);
    p = fmaf(t, p, -0.284496736f);
    p = fmaf(t, p, 0.254829592f);
    p *= t;
    float e = __expf(-z * z);
    float erfz = 1.0f - p * e;
    float s = copysignf(erfz, x);
    return 0.5f * x * (1.0f + s);
}

// ---------------- K0: pair index table (i<<8 | j), tril order ----------------
__global__ void k_pairs(int* __restrict__ pairIJ) {
    int p = blockIdx.x * blockDim.x + threadIdx.x;
    if (p >= NP) return;
    int i = (int)((sqrtf(8.0f * (float)p + 1.0f) - 1.0f) * 0.5f);
    while ((i * (i + 1)) / 2 > p) --i;
    while (((i + 1) * (i + 2)) / 2 <= p) ++i;
    int j = p - (i * (i + 1)) / 2;
    pairIJ[p] = (i << 8) | j;
}

// ---- K0b: pack weights into bf16 MFMA B-fragment layout ---------------------
// fragP  (2 mats x 32 frags x 512): f = wn*16 + s*2 + nt (DPA cols, K=128)
// fragC1 (16 frags x 512):          f = s*2 + wn         (64 cols, K=128)
// fragC2 (8 frags x 512):           f = s*2 + wn         (64 cols, K=64)
__global__ void k_pack(const float* __restrict__ wp1, const float* __restrict__ wp2,
                       const float* __restrict__ wc1, const float* __restrict__ wc2,
                       bf16* __restrict__ fragP, bf16* __restrict__ fragC1,
                       bf16* __restrict__ fragC2) {
    int id = blockIdx.x * 256 + threadIdx.x;
    if (id < 32768) {
        int mat = id >> 14, rem = id & 16383;
        int f = rem >> 9, lane = (rem >> 3) & 63, i = rem & 7;
        int wn = f >> 4, s = (f >> 1) & 7, nt = f & 1;
        int k = s * 16 + (lane >> 5) * 8 + i;
        int col = wn * 64 + nt * 32 + (lane & 31);
        const float* w = mat ? wp2 : wp1;
        fragP[id] = __float2bfloat16(w[k * DPA + col]);
    } else if (id < 40960) {
        int rem = id - 32768;
        int f = rem >> 9, lane = (rem >> 3) & 63, i = rem & 7;
        int s = f >> 1, wn = f & 1;
        int k = s * 16 + (lane >> 5) * 8 + i;
        int col = wn * 32 + (lane & 31);
        fragC1[rem] = __float2bfloat16(wc1[k * DOU + col]);
    } else if (id < 45056) {
        int rem = id - 40960;
        int f = rem >> 9, lane = (rem >> 3) & 63, i = rem & 7;
        int s = f >> 1, wn = f & 1;
        int k = s * 16 + (lane >> 5) * 8 + i;
        int col = wn * 32 + (lane & 31);
        fragC2[rem] = __float2bfloat16(wc2[k * DOU + col]);
    }
}

// ---------------- K1: h = gelu(gelu(x@w1+b1)@w2+b2), bf16 out ----------------
__global__ void k_h(const float* __restrict__ x, const float* __restrict__ w1,
                    const float* __restrict__ b1, const float* __restrict__ w2,
                    const float* __restrict__ b2, bf16* __restrict__ h) {
    __shared__ float h1[4][DPT];
    int t = threadIdx.x;
    int rs = t >> 6;
    int c = t & 63;
    int r = blockIdx.x * 4 + rs;
    const float* xr = x + (size_t)r * DIN;
    float acc = b1[c];
#pragma unroll
    for (int k = 0; k < DIN; ++k) acc += xr[k] * w1[k * DPT + c];
    h1[rs][c] = gelu_exact(acc);
    __syncthreads();
    float acc2 = b2[c];
#pragma unroll
    for (int k = 0; k < DPT; ++k) acc2 += h1[rs][k] * w2[k * DPT + c];
    h[(size_t)r * DPT + c] = __float2bfloat16(gelu_exact(acc2));
}

// -------- K2: e0 = gelu(gelu(xij@wp1+bp1)@wp2+bp2); partial stats ------------
// 1 chunk (128 rows) per block; single 32KB LDS buffer overlaid X/mid/out.
__global__ __launch_bounds__(256) void k_e0m(
    const bf16* __restrict__ h, const int* __restrict__ pairIJ,
    const short8* __restrict__ fragP, const float* __restrict__ bp1,
    const float* __restrict__ bp2, bf16* __restrict__ e0,
    float* __restrict__ part) {
    __shared__ __align__(16) char buf[32768];
    __shared__ float st[1024];
    int t = threadIdx.x;
    int w = t >> 6, l = t & 63;
    int wm = w >> 1, wn = w & 1;
    int l31 = l & 31, lhi = l >> 5;
    int row0 = blockIdx.x * 128;

    for (int i = t; i < 1024; i += 256) st[i] = 0.f;

    // gather xij into swizzled LDS: row rr (256B), slot = 16B sub-block
#pragma unroll
    for (int q = 0; q < 8; ++q) {
        int task = t + 256 * q;
        int rr = task >> 4, slot = task & 15;
        int n = row0 + rr;
        int b = n / NP, p = n - b * NP;
        int ij = pairIJ[p];
        int src = (slot < 8) ? (ij & 255) : (ij >> 8);
        int4v v = *(const int4v*)(h + (((size_t)(b * SS + src)) << 6) + ((slot & 7) << 3));
        *(int4v*)(buf + rr * 256 + ((slot * 16) ^ ((rr & 15) << 4))) = v;
    }
    // B fragments for GEMM1 (coalesced short8 from packed buffer)
    short8 bfr[2][8];
#pragma unroll
    for (int nt = 0; nt < 2; ++nt)
#pragma unroll
        for (int s = 0; s < 8; ++s) bfr[nt][s] = fragP[(wn * 16 + s * 2 + nt) * 64 + l];
    float bias1[2] = {bp1[wn * 64 + l31], bp1[wn * 64 + 32 + l31]};
    __syncthreads();

    const int rA0 = wm * 64 + l31, rA1 = rA0 + 32;
    // ---- GEMM1 ----
    f32x16 acc[2][2];
#pragma unroll
    for (int mt = 0; mt < 2; ++mt)
#pragma unroll
        for (int nt = 0; nt < 2; ++nt)
#pragma unroll
            for (int r = 0; r < 16; ++r) acc[mt][nt][r] = bias1[nt];
#pragma unroll
    for (int s = 0; s < 8; ++s) {
        int kb = s * 32 + lhi * 16;
        short8 a0 = *(const short8*)(buf + rA0 * 256 + (kb ^ ((rA0 & 15) << 4)));
        short8 a1 = *(const short8*)(buf + rA1 * 256 + (kb ^ ((rA1 & 15) << 4)));
        acc[0][0] = MFMA32(a0, bfr[0][s], acc[0][0]);
        acc[0][1] = MFMA32(a0, bfr[1][s], acc[0][1]);
        acc[1][0] = MFMA32(a1, bfr[0][s], acc[1][0]);
        acc[1][1] = MFMA32(a1, bfr[1][s], acc[1][1]);
    }
    __syncthreads();  // all GEMM1 LDS reads done

    // write mid = gelu(acc) into same buffer; load GEMM2 B fragments
#pragma unroll
    for (int mt = 0; mt < 2; ++mt)
#pragma unroll
        for (int nt = 0; nt < 2; ++nt)
#pragma unroll
            for (int r = 0; r < 16; ++r) {
                float v = gelu_exact(acc[mt][nt][r]);
                int row = wm * 64 + mt * 32 + (r & 3) + 8 * (r >> 2) + 4 * lhi;
                int col = wn * 64 + nt * 32 + l31;
                *(bf16*)(buf + row * 256 + ((col * 2) ^ ((row & 15) << 4))) =
                    __float2bfloat16(v);
            }
    short8 bfr2[2][8];
#pragma unroll
    for (int nt = 0; nt < 2; ++nt)
#pragma unroll
        for (int s = 0; s < 8; ++s)
            bfr2[nt][s] = fragP[2048 + (wn * 16 + s * 2 + nt) * 64 + l];
    float bias2[2] = {bp2[wn * 64 + l31], bp2[wn * 64 + 32 + l31]};
    __syncthreads();

    // ---- GEMM2 ----
    f32x16 acc2[2][2];
#pragma unroll
    for (int mt = 0; mt < 2; ++mt)
#pragma unroll
        for (int nt = 0; nt < 2; ++nt)
#pragma unroll
            for (int r = 0; r < 16; ++r) acc2[mt][nt][r] = bias2[nt];
#pragma unroll
    for (int s = 0; s < 8; ++s) {
        int kb = s * 32 + lhi * 16;
        short8 a0 = *(const short8*)(buf + rA0 * 256 + (kb ^ ((rA0 & 15) << 4)));
        short8 a1 = *(const short8*)(buf + rA1 * 256 + (kb ^ ((rA1 & 15) << 4)));
        acc2[0][0] = MFMA32(a0, bfr2[0][s], acc2[0][0]);
        acc2[0][1] = MFMA32(a0, bfr2[1][s], acc2[0][1]);
        acc2[1][0] = MFMA32(a1, bfr2[0][s], acc2[1][0]);
        acc2[1][1] = MFMA32(a1, bfr2[1][s], acc2[1][1]);
    }
    __syncthreads();  // GEMM2 reads done

    // stats + stage outputs into buffer (bf16, swizzled)
    float sum[2] = {0.f, 0.f}, sq[2] = {0.f, 0.f};
#pragma unroll
    for (int mt = 0; mt < 2; ++mt)
#pragma unroll
        for (int nt = 0; nt < 2; ++nt)
#pragma unroll
            for (int r = 0; r < 16; ++r) {
                float v = gelu_exact(acc2[mt][nt][r]);
                sum[nt] += v;
                sq[nt] += v * v;
                int row = wm * 64 + mt * 32 + (r & 3) + 8 * (r >> 2) + 4 * lhi;
                int col = wn * 64 + nt * 32 + l31;
                *(bf16*)(buf + row * 256 + ((col * 2) ^ ((row & 15) << 4))) =
                    __float2bfloat16(v);
            }
    __syncthreads();

    // coalesced 16B stores of e0
#pragma unroll
    for (int q = 0; q < 8; ++q) {
        int task = t + 256 * q;
        int rr = task >> 4, slot = task & 15;
        int4v v = *(const int4v*)(buf + rr * 256 + ((slot * 16) ^ ((rr & 15) << 4)));
        *(int4v*)(e0 + (size_t)(row0 + rr) * DPA + slot * 8) = v;
    }

    // stats reduction
#pragma unroll
    for (int nt = 0; nt < 2; ++nt) {
        sum[nt] += __shfl_xor(sum[nt], 32);
        sq[nt] += __shfl_xor(sq[nt], 32);
    }
    if (l < 32) {
#pragma unroll
        for (int nt = 0; nt < 2; ++nt) {
            st[w * 256 + wn * 64 + nt * 32 + l] = sum[nt];
            st[w * 256 + 128 + wn * 64 + nt * 32 + l] = sq[nt];
        }
    }
    __syncthreads();
    part[(size_t)blockIdx.x * 256 + t] = st[t] + st[256 + t] + st[512 + t] + st[768 + t];
}

// -------- stats finalize: a = g*rstd, d = be - mean*a ------------------------
__global__ void k_stats(const float* __restrict__ part, int nch, int nblk,
                        float* __restrict__ a, float* __restrict__ d,
                        const float* __restrict__ g, const float* __restrict__ be) {
    int c = blockIdx.x;
    __shared__ float ssum[256], ssq[256];
    float s = 0.f, q = 0.f;
    for (int bidx = threadIdx.x; bidx < nblk; bidx += 256) {
        s += part[(size_t)bidx * (2 * nch) + c];
        q += part[(size_t)bidx * (2 * nch) + nch + c];
    }
    ssum[threadIdx.x] = s;
    ssq[threadIdx.x] = q;
    __syncthreads();
    for (int w = 128; w > 0; w >>= 1) {
        if ((int)threadIdx.x < w) {
            ssum[threadIdx.x] += ssum[threadIdx.x + w];
            ssq[threadIdx.x] += ssq[threadIdx.x + w];
        }
        __syncthreads();
    }
    if (threadIdx.x == 0) {
        float mean = ssum[0] / (float)NROWS;
        float var = ssq[0] / (float)NROWS - mean * mean;
        float rstd = rsqrtf(var + EPSF);
        float aa = g[c] * rstd;
        a[c] = aa;
        d[c] = be[c] - mean * aa;
    }
}

// -------- K4: e1 = bn0(e0)@wc1 + bc1 (MFMA); partial stats -------------------
__global__ __launch_bounds__(256) void k_e1m(
    const bf16* __restrict__ e0, const float* __restrict__ a0,
    const float* __restrict__ d0, const short8* __restrict__ fragC1,
    const float* __restrict__ bc1, bf16* __restrict__ e1,
    float* __restrict__ part) {
    __shared__ __align__(16) char buf[32768];
    __shared__ float st[512];
    int t = threadIdx.x;
    int w = t >> 6, l = t & 63;
    int wm = w >> 1, wn = w & 1;
    int l31 = l & 31, lhi = l >> 5;
    int row0 = blockIdx.x * 128;

    for (int i = t; i < 512; i += 256) st[i] = 0.f;

    int slot = t & 15, c0 = slot * 8;  // fixed channel slice per thread
    f32x4 aLo = *(const f32x4*)(a0 + c0), aHi = *(const f32x4*)(a0 + c0 + 4);
    f32x4 dLo = *(const f32x4*)(d0 + c0), dHi = *(const f32x4*)(d0 + c0 + 4);
    float A[8] = {aLo[0], aLo[1], aLo[2], aLo[3], aHi[0], aHi[1], aHi[2], aHi[3]};
    float D[8] = {dLo[0], dLo[1], dLo[2], dLo[3], dHi[0], dHi[1], dHi[2], dHi[3]};

#pragma unroll
    for (int q = 0; q < 8; ++q) {
        int rr = (t >> 4) + 16 * q;
        short8 raw = *(const short8*)(e0 + (size_t)(row0 + rr) * DPA + c0);
        short8 outv;
#pragma unroll
        for (int i = 0; i < 8; ++i)
            outv[i] = (short)bfb(fmaf(bf2f(raw[i]), A[i], D[i]));
        *(short8*)(buf + rr * 256 + ((slot * 16) ^ ((rr & 15) << 4))) = outv;
    }
    short8 bfr[8];
#pragma unroll
    for (int s = 0; s < 8; ++s) bfr[s] = fragC1[(s * 2 + wn) * 64 + l];
    float bias = bc1[wn * 32 + l31];
    __syncthreads();

    const int rA0 = wm * 64 + l31, rA1 = rA0 + 32;
    f32x16 acc[2];
#pragma unroll
    for (int mt = 0; mt < 2; ++mt)
#pragma unroll
        for (int r = 0; r < 16; ++r) acc[mt][r] = bias;
#pragma unroll
    for (int s = 0; s < 8; ++s) {
        int kb = s * 32 + lhi * 16;
        short8 af0 = *(const short8*)(buf + rA0 * 256 + (kb ^ ((rA0 & 15) << 4)));
        short8 af1 = *(const short8*)(buf + rA1 * 256 + (kb ^ ((rA1 & 15) << 4)));
        acc[0] = MFMA32(af0, bfr[s], acc[0]);
        acc[1] = MFMA32(af1, bfr[s], acc[1]);
    }
    __syncthreads();

    float sum = 0.f, sq = 0.f;
#pragma unroll
    for (int mt = 0; mt < 2; ++mt)
#pragma unroll
        for (int r = 0; r < 16; ++r) {
            float v = acc[mt][r];
            sum += v;
            sq += v * v;
            int row = wm * 64 + mt * 32 + (r & 3) + 8 * (r >> 2) + 4 * lhi;
            int col = wn * 32 + l31;
            *(bf16*)(buf + row * 128 + ((col * 2) ^ ((row & 7) << 4))) =
                __float2bfloat16(v);
        }
    __syncthreads();

#pragma unroll
    for (int q = 0; q < 4; ++q) {
        int rr = (t >> 3) + 32 * q;
        int s8 = t & 7;
        int4v v = *(const int4v*)(buf + rr * 128 + ((s8 * 16) ^ ((rr & 7) << 4)));
        *(int4v*)(e1 + (size_t)(row0 + rr) * DOU + s8 * 8) = v;
    }

    sum += __shfl_xor(sum, 32);
    sq += __shfl_xor(sq, 32);
    if (l < 32) {
        st[w * 128 + wn * 32 + l] = sum;
        st[w * 128 + 64 + wn * 32 + l] = sq;
    }
    __syncthreads();
    if (t < 128)
        part[(size_t)blockIdx.x * 128 + t] = st[t] + st[128 + t] + st[256 + t] + st[384 + t];
}

// -------- K6: e2 = gelu(bn1(e1))@wc2 + bc2 (MFMA); partial stats -------------
__global__ __launch_bounds__(256) void k_e2m(
    const bf16* __restrict__ e1, const float* __restrict__ a1,
    const float* __restrict__ d1, const short8* __restrict__ fragC2,
    const float* __restrict__ bc2, bf16* __restrict__ e2,
    float* __restrict__ part) {
    __shared__ __align__(16) char buf[16384];
    __shared__ float st[512];
    int t = threadIdx.x;
    int w = t >> 6, l = t & 63;
    int wm = w >> 1, wn = w & 1;
    int l31 = l & 31, lhi = l >> 5;
    int row0 = blockIdx.x * 128;

    for (int i = t; i < 512; i += 256) st[i] = 0.f;

    int slot = t & 7, c0 = slot * 8;
    f32x4 aLo = *(const f32x4*)(a1 + c0), aHi = *(const f32x4*)(a1 + c0 + 4);
    f32x4 dLo = *(const f32x4*)(d1 + c0), dHi = *(const f32x4*)(d1 + c0 + 4);
    float A[8] = {aLo[0], aLo[1], aLo[2], aLo[3], aHi[0], aHi[1], aHi[2], aHi[3]};
    float D[8] = {dLo[0], dLo[1], dLo[2], dLo[3], dHi[0], dHi[1], dHi[2], dHi[3]};

#pragma unroll
    for (int q = 0; q < 4; ++q) {
        int rr = (t >> 3) + 32 * q;
        short8 raw = *(const short8*)(e1 + (size_t)(row0 + rr) * DOU + c0);
        short8 outv;
#pragma unroll
        for (int i = 0; i < 8; ++i)
            outv[i] = (short)bfb(gelu_exact(fmaf(bf2f(raw[i]), A[i], D[i])));
        *(short8*)(buf + rr * 128 + ((slot * 16) ^ ((rr & 7) << 4))) = outv;
    }
    short8 bfr[4];
#pragma unroll
    for (int s = 0; s < 4; ++s) bfr[s] = fragC2[(s * 2 + wn) * 64 + l];
    float bias = bc2[wn * 32 + l31];
    __syncthreads();

    const int rA0 = wm * 64 + l31, rA1 = rA0 + 32;
    f32x16 acc[2];
#pragma unroll
    for (int mt = 0; mt < 2; ++mt)
#pragma unroll
        for (int r = 0; r < 16; ++r) acc[mt][r] = bias;
#pragma unroll
    for (int s = 0; s < 4; ++s) {
        int kb = s * 32 + lhi * 16;
        short8 af0 = *(const short8*)(buf + rA0 * 128 + (kb ^ ((rA0 & 7) << 4)));
        short8 af1 = *(const short8*)(buf + rA1 * 128 + (kb ^ ((rA1 & 7) << 4)));
        acc[0] = MFMA32(af0, bfr[s], acc[0]);
        acc[1] = MFMA32(af1, bfr[s], acc[1]);
    }
    __syncthreads();

    float sum = 0.f, sq = 0.f;
#pragma unroll
    for (int mt = 0; mt < 2; ++mt)
#pragma unroll
        for (int r = 0; r < 16; ++r) {
            float v = acc[mt][r];
            sum += v;
            sq += v * v;
            int row = wm * 64 + mt * 32 + (r & 3) + 8 * (r >> 2) + 4 * lhi;
            int col = wn * 32 + l31;
            *(bf16*)(buf + row * 128 + ((col * 2) ^ ((row & 7) << 4))) =
                __float2bfloat16(v);
        }
    __syncthreads();

#pragma unroll
    for (int q = 0; q < 4; ++q) {
        int rr = (t >> 3) + 32 * q;
        int s8 = t & 7;
        int4v v = *(const int4v*)(buf + rr * 128 + ((s8 * 16) ^ ((rr & 7) << 4)));
        *(int4v*)(e2 + (size_t)(row0 + rr) * DOU + s8 * 8) = v;
    }

    sum += __shfl_xor(sum, 32);
    sq += __shfl_xor(sq, 32);
    if (l < 32) {
        st[w * 128 + wn * 32 + l] = sum;
        st[w * 128 + 64 + wn * 32 + l] = sq;
    }
    __syncthreads();
    if (t < 128)
        part[(size_t)blockIdx.x * 128 + t] = st[t] + st[128 + t] + st[256 + t] + st[384 + t];
}

// -------- K8: y[b,i,j,:] = y[b,j,i,:] = bn2(e2), vectorized ------------------
__global__ void k_out(const bf16* __restrict__ e2, const int* __restrict__ pairIJ,
                      const float* __restrict__ a2, const float* __restrict__ d2,
                      float* __restrict__ y) {
    int t = threadIdx.x;
    int n = blockIdx.x * 32 + (t >> 3);
    int c0 = (t & 7) * 8;
    int b = n / NP, p = n - b * NP;
    int ij = pairIJ[p];
    int ii = ij >> 8, jj = ij & 255;
    short8 raw = *(const short8*)(e2 + (size_t)n * DOU + c0);
    f32x4 aLo = *(const f32x4*)(a2 + c0), aHi = *(const f32x4*)(a2 + c0 + 4);
    f32x4 dLo = *(const f32x4*)(d2 + c0), dHi = *(const f32x4*)(d2 + c0 + 4);
    f32x4 v0, v1;
#pragma unroll
    for (int i = 0; i < 4; ++i) v0[i] = fmaf(bf2f(raw[i]), aLo[i], dLo[i]);
#pragma unroll
    for (int i = 0; i < 4; ++i) v1[i] = fmaf(bf2f(raw[4 + i]), aHi[i], dHi[i]);
    float* y1 = y + ((size_t)(b * SS + ii) * SS + jj) * DOU + c0;
    float* y2 = y + ((size_t)(b * SS + jj) * SS + ii) * DOU + c0;
    *(f32x4*)y1 = v0;
    *(f32x4*)(y1 + 4) = v1;
    *(f32x4*)y2 = v0;
    *(f32x4*)(y2 + 4) = v1;
}

extern "C" void kernel_launch(void* const* d_in, const int* in_sizes, int n_in,
                              void* d_out, int out_size, void* d_ws, size_t ws_size,
                              hipStream_t stream) {
    const float* x   = (const float*)d_in[0];
    const float* w1  = (const float*)d_in[1];
    const float* b1  = (const float*)d_in[2];
    const float* w2  = (const float*)d_in[3];
    const float* b2  = (const float*)d_in[4];
    const float* wp1 = (const float*)d_in[5];
    const float* bp1 = (const float*)d_in[6];
    const float* wp2 = (const float*)d_in[7];
    const float* bp2 = (const float*)d_in[8];
    const float* g0  = (const float*)d_in[9];
    const float* be0 = (const float*)d_in[10];
    const float* wc1 = (const float*)d_in[11];
    const float* bc1 = (const float*)d_in[12];
    const float* g1  = (const float*)d_in[13];
    const float* be1 = (const float*)d_in[14];
    const float* wc2 = (const float*)d_in[15];
    const float* bc2 = (const float*)d_in[16];
    const float* g2  = (const float*)d_in[17];
    const float* be2 = (const float*)d_in[18];

    char* ws = (char*)d_ws;
    const size_t OFF_PAIR   = 0;         // 33024
    const size_t OFF_H      = 33280;     // 512KB bf16
    const size_t OFF_PART   = 557568;    // 2064*256*4 = 2113536
    const size_t OFF_FRAGP  = 2671104;   // 65536
    const size_t OFF_FRAGC1 = 2736640;   // 16384
    const size_t OFF_FRAGC2 = 2753024;   // 8192
    const size_t OFF_A0 = 2761216, OFF_D0 = 2761728;
    const size_t OFF_A1 = 2762240, OFF_D1 = 2762752;
    const size_t OFF_A2 = 2763264, OFF_D2 = 2763776;
    const size_t OFF_E2 = 2764288;       // 33816576

    int*   pairIJ = (int*)(ws + OFF_PAIR);
    bf16*  h      = (bf16*)(ws + OFF_H);
    float* part   = (float*)(ws + OFF_PART);
    bf16*  fragP  = (bf16*)(ws + OFF_FRAGP);
    bf16*  fragC1 = (bf16*)(ws + OFF_FRAGC1);
    bf16*  fragC2 = (bf16*)(ws + OFF_FRAGC2);
    float* a0 = (float*)(ws + OFF_A0);
    float* d0 = (float*)(ws + OFF_D0);
    float* a1 = (float*)(ws + OFF_A1);
    float* d1 = (float*)(ws + OFF_D1);
    float* a2 = (float*)(ws + OFF_A2);
    float* d2 = (float*)(ws + OFF_D2);
    bf16*  e2 = (bf16*)(ws + OFF_E2);

    bf16* e0 = (bf16*)d_out;
    bf16* e1 = (bf16*)((char*)d_out + (size_t)NROWS * DPA * sizeof(bf16));
    float* y = (float*)d_out;

    k_pairs<<<(NP + 255) / 256, 256, 0, stream>>>(pairIJ);
    k_pack<<<176, 256, 0, stream>>>(wp1, wp2, wc1, wc2, fragP, fragC1, fragC2);
    k_h<<<(BB * SS) / 4, 256, 0, stream>>>(x, w1, b1, w2, b2, h);
    k_e0m<<<NCHUNK, 256, 0, stream>>>(h, pairIJ, (const short8*)fragP, bp1, bp2, e0, part);
    k_stats<<<DPA, 256, 0, stream>>>(part, DPA, NCHUNK, a0, d0, g0, be0);
    k_e1m<<<NCHUNK, 256, 0, stream>>>(e0, a0, d0, (const short8*)fragC1, bc1, e1, part);
    k_stats<<<DOU, 256, 0, stream>>>(part, DOU, NCHUNK, a1, d1, g1, be1);
    k_e2m<<<NCHUNK, 256, 0, stream>>>(e1, a1, d1, (const short8*)fragC2, bc2, e2, part);
    k_stats<<<DOU, 256, 0, stream>>>(part, DOU, NCHUNK, a2, d2, g2, be2);
    k_out<<<NROWS / 32, 256, 0, stream>>>(e2, pairIJ, a2, d2, y);
}